// Round 1
// baseline (277.461 us; speedup 1.0000x reference)
//
#include <hip/hip_runtime.h>
#include <math.h>

#define NB   2
#define NPTS 262144      // 64^3 points per batch
#define NF   64
#define NCI  32
#define NCO  32
#define TWO_PI 6.283185307179586f

// ---------------------------------------------------------------------------
// GELU (tanh approximation, matching jax.nn.gelu default)
// ---------------------------------------------------------------------------
__device__ __forceinline__ float gelu_tanh(float v) {
    float v3 = v * v * v;
    float z  = 0.7978845608028654f * (v + 0.044715f * v3);
    float e  = __expf(2.0f * z);
    float th = 1.0f - 2.0f / (e + 1.0f);   // tanh(z)
    return 0.5f * v * (1.0f + th);
}

// ---------------------------------------------------------------------------
// Pass 1: partial W[i,g] = sum_p a[p,i] * exp(-2*pi*i * x[p].mx[g])
// One block accumulates over NPTS/PB points, writes [re(2048)|im(2048)] partial.
// grid = NB*PB blocks, 256 threads.
// ---------------------------------------------------------------------------
__global__ __launch_bounds__(256)
void pass1_kernel(const float* __restrict__ a, const float* __restrict__ x,
                  const float* __restrict__ mx, float* __restrict__ part, int PB)
{
    __shared__ __align__(16) float mxs[NF * 3];
    __shared__ __align__(16) float xs[64 * 3];
    __shared__ __align__(16) float aT[64][NCI];
    __shared__ __align__(16) float Xre[64][NF];
    __shared__ __align__(16) float Xim[64][NF];

    const int t   = threadIdx.x;
    const int blk = blockIdx.x;
    const int b   = blk / PB;
    const int pb  = blk % PB;
    const int npb = NPTS / PB;
    const long base = (long)b * NPTS + (long)pb * npb;

    if (t < NF * 3) mxs[t] = mx[t];

    const int i0 = (t >> 4) * 2;   // 0,2,...,30
    const int g0 = (t & 15) * 4;   // 0,4,...,60

    float wr[2][4] = {{0.f,0.f,0.f,0.f},{0.f,0.f,0.f,0.f}};
    float wi[2][4] = {{0.f,0.f,0.f,0.f},{0.f,0.f,0.f,0.f}};

    for (int c = 0; c < npb; c += 64) {
        const long p0 = base + c;
        __syncthreads();
        if (t < 192) xs[t] = x[p0 * 3 + t];
        {
            const float4* ag = (const float4*)(a + p0 * NCI);
            float4* as = (float4*)&aT[0][0];
            as[t]       = ag[t];
            as[t + 256] = ag[t + 256];
        }
        __syncthreads();
        for (int idx = t; idx < 64 * NF; idx += 256) {
            int k = idx >> 6, g = idx & 63;
            float ph = xs[k*3]*mxs[g*3] + xs[k*3+1]*mxs[g*3+1] + xs[k*3+2]*mxs[g*3+2];
            float w  = -TWO_PI * ph;
            Xre[k][g] = __cosf(w);
            Xim[k][g] = __sinf(w);
        }
        __syncthreads();
        #pragma unroll 8
        for (int k = 0; k < 64; ++k) {
            float2 a01 = *(const float2*)&aT[k][i0];
            float4 xr  = *(const float4*)&Xre[k][g0];
            float4 xi  = *(const float4*)&Xim[k][g0];
            wr[0][0] += a01.x * xr.x; wr[0][1] += a01.x * xr.y;
            wr[0][2] += a01.x * xr.z; wr[0][3] += a01.x * xr.w;
            wi[0][0] += a01.x * xi.x; wi[0][1] += a01.x * xi.y;
            wi[0][2] += a01.x * xi.z; wi[0][3] += a01.x * xi.w;
            wr[1][0] += a01.y * xr.x; wr[1][1] += a01.y * xr.y;
            wr[1][2] += a01.y * xr.z; wr[1][3] += a01.y * xr.w;
            wi[1][0] += a01.y * xi.x; wi[1][1] += a01.y * xi.y;
            wi[1][2] += a01.y * xi.z; wi[1][3] += a01.y * xi.w;
        }
    }

    float* pr = part + (long)blk * 4096;
    #pragma unroll
    for (int di = 0; di < 2; ++di) {
        *(float4*)&pr[(i0 + di) * NF + g0] =
            make_float4(wr[di][0], wr[di][1], wr[di][2], wr[di][3]);
        *(float4*)&pr[2048 + (i0 + di) * NF + g0] =
            make_float4(wi[di][0], wi[di][1], wi[di][2], wi[di][3]);
    }
}

// ---------------------------------------------------------------------------
// Reduce partials -> Wf[b][re|im] (2 * 4096 floats)
// grid = 32 blocks * 256 threads = 8192 threads (one per output element)
// ---------------------------------------------------------------------------
__global__ __launch_bounds__(256)
void reduce_kernel(const float* __restrict__ part, float* __restrict__ Wf, int PB)
{
    int e = blockIdx.x * 256 + threadIdx.x;
    if (e >= NB * 4096) return;
    int b = e >> 12;
    int j = e & 4095;
    const float* p = part + (long)b * PB * 4096 + j;
    float s = 0.f;
    for (int pb = 0; pb < PB; ++pb) s += p[(long)pb * 4096];
    Wf[e] = s;
}

// ---------------------------------------------------------------------------
// V[b][o][g] = sum_i Q[o,i] * W[b][i,g],  Q = Mu^T Ma   (complex, Q real)
// grid = NB blocks
// ---------------------------------------------------------------------------
__global__ __launch_bounds__(256)
void vmat_kernel(const float* __restrict__ Wf, const float* __restrict__ ma,
                 const float* __restrict__ mu, float* __restrict__ V)
{
    __shared__ float Ws[4096];
    __shared__ float Mas[NF * NCI];
    __shared__ float Mus[NF * NCO];
    __shared__ float Qs[NCO][NCI];

    const int t = threadIdx.x;
    const int b = blockIdx.x;

    for (int idx = t; idx < 4096; idx += 256) Ws[idx] = Wf[b * 4096 + idx];
    for (int idx = t; idx < NF * NCI; idx += 256) { Mas[idx] = ma[idx]; Mus[idx] = mu[idx]; }
    __syncthreads();

    for (int idx = t; idx < NCO * NCI; idx += 256) {
        int o = idx >> 5, i = idx & 31;
        float s = 0.f;
        for (int f = 0; f < NF; ++f) s += Mus[f * NCO + o] * Mas[f * NCI + i];
        Qs[o][i] = s;
    }
    __syncthreads();

    for (int idx = t; idx < NCO * NF; idx += 256) {
        int o = idx >> 6, g = idx & 63;
        float sr = 0.f, si = 0.f;
        for (int i = 0; i < NCI; ++i) {
            float q = Qs[o][i];
            sr += q * Ws[i * NF + g];
            si += q * Ws[2048 + i * NF + g];
        }
        V[(long)b * 4096 + idx]        = sr;
        V[(long)b * 4096 + 2048 + idx] = si;
    }
}

// ---------------------------------------------------------------------------
// Pass 2: u[p,o] = Re(sum_g V[o,g] * exp(+2*pi*i * x[p].my[g])) / N
//         h = u + a.fc_w + fc_b ; out = gelu(h)
// grid = 1024 blocks * 256 threads, 2 points per thread
// ---------------------------------------------------------------------------
__global__ __launch_bounds__(256)
void pass2_kernel(const float* __restrict__ a, const float* __restrict__ x,
                  const float* __restrict__ V, const float* __restrict__ fcw,
                  const float* __restrict__ fcb, const float* __restrict__ my,
                  float* __restrict__ out)
{
    __shared__ __align__(16) float Vre[NCO][NF];
    __shared__ __align__(16) float Vim[NCO][NF];
    __shared__ __align__(16) float Wsw[NCI][NCO];
    __shared__ float bs[NCO];
    __shared__ float mys[NF * 3];

    const int t   = threadIdx.x;
    const int blk = blockIdx.x;          // 512 blocks per batch
    const int b   = blk >> 9;
    const int lb  = blk & 511;
    const long pbase = (long)b * NPTS + (long)lb * 512;

    for (int idx = t; idx < 2048; idx += 256) {
        ((float*)Vre)[idx] = V[(long)b * 4096 + idx];
        ((float*)Vim)[idx] = V[(long)b * 4096 + 2048 + idx];
    }
    for (int idx = t; idx < NCI * NCO; idx += 256) ((float*)Wsw)[idx] = fcw[idx];
    if (t < NCO) bs[t] = fcb[t];
    if (t < NF * 3) mys[t] = my[t];
    __syncthreads();

    float xx[2][3];
    #pragma unroll
    for (int q = 0; q < 2; ++q) {
        long P = pbase + t + q * 256;
        xx[q][0] = x[P * 3];
        xx[q][1] = x[P * 3 + 1];
        xx[q][2] = x[P * 3 + 2];
    }

    float u[2][NCO];
    {
        float ar[2][NCI];
        #pragma unroll
        for (int q = 0; q < 2; ++q) {
            const float4* ap = (const float4*)(a + (pbase + t + q * 256) * NCI);
            #pragma unroll
            for (int r = 0; r < 8; ++r) {
                float4 v = ap[r];
                ar[q][r * 4]     = v.x; ar[q][r * 4 + 1] = v.y;
                ar[q][r * 4 + 2] = v.z; ar[q][r * 4 + 3] = v.w;
            }
        }
        #pragma unroll
        for (int q = 0; q < 2; ++q)
            #pragma unroll
            for (int o = 0; o < NCO; ++o) u[q][o] = bs[o];
        #pragma unroll
        for (int i = 0; i < NCI; ++i) {
            float a0 = ar[0][i], a1 = ar[1][i];
            #pragma unroll
            for (int o4 = 0; o4 < NCO; o4 += 4) {
                float4 w4 = *(const float4*)&Wsw[i][o4];
                u[0][o4]     += a0 * w4.x; u[0][o4 + 1] += a0 * w4.y;
                u[0][o4 + 2] += a0 * w4.z; u[0][o4 + 3] += a0 * w4.w;
                u[1][o4]     += a1 * w4.x; u[1][o4 + 1] += a1 * w4.y;
                u[1][o4 + 2] += a1 * w4.z; u[1][o4 + 3] += a1 * w4.w;
            }
        }
        // pre-scale residual by N (exact: power of two); divide everything at end
        #pragma unroll
        for (int q = 0; q < 2; ++q)
            #pragma unroll
            for (int o = 0; o < NCO; ++o) u[q][o] *= 262144.0f;
    }

    for (int g4 = 0; g4 < NF; g4 += 4) {
        float yr[2][4], yi[2][4];
        #pragma unroll
        for (int q = 0; q < 2; ++q) {
            #pragma unroll
            for (int j = 0; j < 4; ++j) {
                int g = g4 + j;
                float ph = xx[q][0]*mys[g*3] + xx[q][1]*mys[g*3+1] + xx[q][2]*mys[g*3+2];
                float w  = TWO_PI * ph;
                yr[q][j] = __cosf(w);
                yi[q][j] = __sinf(w);
            }
        }
        #pragma unroll
        for (int o = 0; o < NCO; ++o) {
            float4 vr = *(const float4*)&Vre[o][g4];
            float4 vi = *(const float4*)&Vim[o][g4];
            u[0][o] += vr.x*yr[0][0] + vr.y*yr[0][1] + vr.z*yr[0][2] + vr.w*yr[0][3]
                     - vi.x*yi[0][0] - vi.y*yi[0][1] - vi.z*yi[0][2] - vi.w*yi[0][3];
            u[1][o] += vr.x*yr[1][0] + vr.y*yr[1][1] + vr.z*yr[1][2] + vr.w*yr[1][3]
                     - vi.x*yi[1][0] - vi.y*yi[1][1] - vi.z*yi[1][2] - vi.w*yi[1][3];
        }
    }

    const float invN = 1.0f / 262144.0f;
    #pragma unroll
    for (int q = 0; q < 2; ++q) {
        long P = pbase + t + q * 256;
        #pragma unroll
        for (int o4 = 0; o4 < NCO; o4 += 4) {
            float4 ov;
            ov.x = gelu_tanh(u[q][o4]     * invN);
            ov.y = gelu_tanh(u[q][o4 + 1] * invN);
            ov.z = gelu_tanh(u[q][o4 + 2] * invN);
            ov.w = gelu_tanh(u[q][o4 + 3] * invN);
            *(float4*)&out[P * NCO + o4] = ov;
        }
    }
}

// ---------------------------------------------------------------------------
extern "C" void kernel_launch(void* const* d_in, const int* in_sizes, int n_in,
                              void* d_out, int out_size, void* d_ws, size_t ws_size,
                              hipStream_t stream)
{
    const float* a   = (const float*)d_in[0];
    const float* x   = (const float*)d_in[1];
    const float* ma  = (const float*)d_in[3];
    const float* mx  = (const float*)d_in[4];
    const float* my  = (const float*)d_in[5];
    const float* mu  = (const float*)d_in[6];
    const float* fcw = (const float*)d_in[7];
    const float* fcb = (const float*)d_in[8];
    float* out = (float*)d_out;

    // pick the largest partial count that fits in the workspace
    int PB = 256;
    while (PB > 32) {
        size_t need = ((size_t)NB * PB * 4096 + 16384) * sizeof(float);
        if (need <= ws_size) break;
        PB >>= 1;
    }
    float* part = (float*)d_ws;
    float* Wf   = part + (size_t)NB * PB * 4096;
    float* V    = Wf + 8192;

    pass1_kernel<<<NB * PB, 256, 0, stream>>>(a, x, mx, part, PB);
    reduce_kernel<<<32, 256, 0, stream>>>(part, Wf, PB);
    vmat_kernel<<<NB, 256, 0, stream>>>(Wf, ma, mu, V);
    pass2_kernel<<<1024, 256, 0, stream>>>(a, x, V, fcw, fcb, my, out);
}

// Round 2
// 86.247 us; speedup vs baseline: 3.2171x; 3.2171x over previous
//
#include <hip/hip_runtime.h>
#include <math.h>

#define NB   2
#define NPTS 262144      // 64^3 points per batch

typedef __attribute__((ext_vector_type(8))) __bf16 bf16x8;
typedef __attribute__((ext_vector_type(4))) float  f32x4;

// ---------------------------------------------------------------------------
// GELU (tanh approximation, matching jax.nn.gelu default approximate=True)
// ---------------------------------------------------------------------------
__device__ __forceinline__ float gelu_tanh(float v) {
    float v3 = v * v * v;
    float z  = 0.7978845608028654f * (v + 0.044715f * v3);
    float e  = __expf(2.0f * z);
    float th = 1.0f - 2.0f / (e + 1.0f);   // tanh(z)
    return 0.5f * v * (1.0f + th);
}

__device__ __forceinline__ unsigned short bf16_rn(float f) {
    unsigned u = __builtin_bit_cast(unsigned, f);
    u += 0x7fffu + ((u >> 16) & 1u);
    return (unsigned short)(u >> 16);
}

// ---------------------------------------------------------------------------
// Pass 1: per-block partial of
//   C[i,g] = sum_p a[p,i]*cos(2pi x.mx[g]),  S[i,g] = sum_p a[p,i]*sin(2pi x.mx[g])
// (W = C - iS).  MFMA 16x16x32: M=i (2 tiles), N=g (4 tiles re + 4 sin), K=points.
// Partial layout per block: [i(32) * 128 + c], c<64: C, c>=64: S.
// grid = NB*NPB blocks, 256 threads (4 waves, each wave independent 32-pt chunks).
// ---------------------------------------------------------------------------
__global__ __launch_bounds__(256)
void pass1_kernel(const float* __restrict__ a, const float* __restrict__ x,
                  const float* __restrict__ mx, float* __restrict__ part, int NPB)
{
    __shared__ float4 xs[4][32];
    __shared__ float wsum[32 * 129];

    const int t = threadIdx.x, wave = t >> 6, lane = t & 63;
    const int l15 = lane & 15, l4 = lane >> 4;
    const int blk = blockIdx.x, b = blk / NPB, pb = blk % NPB;
    const int ppb = NPTS / NPB;
    const int chunks = ppb >> 5;
    const long base = (long)b * NPTS + (long)pb * ppb;

    // per-lane mx triplets for g = l15 + 16*ct
    float m0[4], m1[4], m2[4];
    #pragma unroll
    for (int ct = 0; ct < 4; ++ct) {
        int g = l15 + 16 * ct;
        m0[ct] = mx[g*3]; m1[ct] = mx[g*3+1]; m2[ct] = mx[g*3+2];
    }

    f32x4 acc[2][8];
    #pragma unroll
    for (int rt = 0; rt < 2; ++rt)
        #pragma unroll
        for (int ct = 0; ct < 8; ++ct)
            acc[rt][ct] = f32x4{0.f, 0.f, 0.f, 0.f};

    for (int ci = wave; ci < chunks; ci += 4) {
        const long p0 = base + ((long)ci << 5);
        if (lane < 32) {
            const float* xq = x + (p0 + lane) * 3;
            xs[wave][lane] = make_float4(xq[0], xq[1], xq[2], 0.f);
        }
        // A operand: A[m=i][k=p_local], lane: i = l15(+16rt), p_local = l4*8+j
        float areg[2][8];
        #pragma unroll
        for (int rt = 0; rt < 2; ++rt)
            #pragma unroll
            for (int j = 0; j < 8; ++j)
                areg[rt][j] = a[(p0 + l4*8 + j) * 32 + l15 + 16*rt];
        bf16x8 afr[2];
        #pragma unroll
        for (int rt = 0; rt < 2; ++rt)
            #pragma unroll
            for (int j = 0; j < 8; ++j)
                afr[rt][j] = (__bf16)areg[rt][j];

        float4 xp[8];
        #pragma unroll
        for (int j = 0; j < 8; ++j) xp[j] = xs[wave][l4*8 + j];

        #pragma unroll
        for (int ct = 0; ct < 4; ++ct) {
            // B operand: B[k=p_local][n=g], lane: g = l15+16ct, p_local = l4*8+j
            bf16x8 bc, bs;
            #pragma unroll
            for (int j = 0; j < 8; ++j) {
                float d = xp[j].x*m0[ct] + xp[j].y*m1[ct] + xp[j].z*m2[ct];
                // v_sin/v_cos take revolutions: cos(2*pi*d), sin(2*pi*d)
                bc[j] = (__bf16)__builtin_amdgcn_cosf(d);
                bs[j] = (__bf16)__builtin_amdgcn_sinf(d);
            }
            #pragma unroll
            for (int rt = 0; rt < 2; ++rt) {
                acc[rt][ct]   = __builtin_amdgcn_mfma_f32_16x16x32_bf16(afr[rt], bc, acc[rt][ct],   0, 0, 0);
                acc[rt][ct+4] = __builtin_amdgcn_mfma_f32_16x16x32_bf16(afr[rt], bs, acc[rt][ct+4], 0, 0, 0);
            }
        }
    }

    // cross-wave reduction in LDS (padded stride 129 to soften bank conflicts)
    for (int w = 0; w < 4; ++w) {
        if (wave == w) {
            #pragma unroll
            for (int rt = 0; rt < 2; ++rt)
                #pragma unroll
                for (int ct = 0; ct < 8; ++ct)
                    #pragma unroll
                    for (int r = 0; r < 4; ++r) {
                        int i = 16*rt + l4*4 + r;
                        int c = ((ct & 3) * 16) + l15 + ((ct & 4) ? 64 : 0);
                        int id = i * 129 + c;
                        float v = acc[rt][ct][r];
                        if (w == 0) wsum[id] = v; else wsum[id] += v;
                    }
        }
        __syncthreads();
    }
    for (int idx = t; idx < 4096; idx += 256) {
        int i = idx >> 7, c = idx & 127;
        part[(long)blk * 4096 + idx] = wsum[i * 129 + c];
    }
}

// ---------------------------------------------------------------------------
// Reduce partials -> Wf[b][4096].  grid = NB*128 blocks; block covers 32 j's,
// 8 threads per j split the NPB partials, LDS tree-combine. Deterministic.
// ---------------------------------------------------------------------------
__global__ __launch_bounds__(256)
void reduceW_kernel(const float* __restrict__ part, float* __restrict__ Wf, int NPB)
{
    __shared__ float red[8][33];
    const int t = threadIdx.x;
    const int b = blockIdx.x >> 7;
    const int jb = (blockIdx.x & 127) * 32;
    const int jj = jb + (t & 31), seg = t >> 5;
    const float* p = part + (long)b * NPB * 4096 + jj;
    float s = 0.f;
    for (int pb = seg; pb < NPB; pb += 8) s += p[(long)pb * 4096];
    red[seg][t & 31] = s;
    __syncthreads();
    if (t < 32) {
        float r = 0.f;
        #pragma unroll
        for (int q = 0; q < 8; ++q) r += red[q][t];
        Wf[b * 4096 + jb + t] = r;
    }
}

// ---------------------------------------------------------------------------
// vmat: Q[o,i] = sum_f mu[f,o]*ma[f,i]; build bf16 B-matrix for pass2:
//   Vb[k,o]: k<64: (Q.C)[o,g=k]/N ; 64..127: (Q.S)[o,g=k-64]/N ; 128..159: fc_w[k-128,o]
// ---------------------------------------------------------------------------
__global__ __launch_bounds__(256)
void vmat_kernel(const float* __restrict__ Wf, const float* __restrict__ ma,
                 const float* __restrict__ mu, const float* __restrict__ fcw,
                 unsigned short* __restrict__ Vb)
{
    __shared__ float Ws[4096];
    __shared__ float Mas[64 * 32], Mus[64 * 32];
    __shared__ float Qs[32][32];
    const int t = threadIdx.x, b = blockIdx.x;

    for (int i = t; i < 4096; i += 256) Ws[i] = Wf[b * 4096 + i];
    for (int i = t; i < 2048; i += 256) { Mas[i] = ma[i]; Mus[i] = mu[i]; }
    __syncthreads();
    for (int i = t; i < 1024; i += 256) {
        int o = i >> 5, ii = i & 31;
        float s = 0.f;
        for (int f = 0; f < 64; ++f) s += Mus[f*32 + o] * Mas[f*32 + ii];
        Qs[o][ii] = s;
    }
    __syncthreads();
    const float invN = 1.f / 262144.f;
    for (int i = t; i < 5120; i += 256) {
        int k = i >> 5, o = i & 31;
        float v;
        if (k < 128) {
            int g = k & 63, off = (k >= 64) ? 64 : 0;
            float s = 0.f;
            for (int q = 0; q < 32; ++q) s += Qs[o][q] * Ws[q*128 + off + g];
            v = s * invN;
        } else {
            v = fcw[(k - 128) * 32 + o];
        }
        Vb[b * 5120 + i] = bf16_rn(v);
    }
}

// ---------------------------------------------------------------------------
// Pass 2: u[p,o] = sum_k A[p,k]*Vb[k,o],  A = [cos | sin | a] (K=160),
// then +bias, gelu. MFMA 16x16x32, 32 points per wave-chunk.
// grid = NB*512 blocks, 256 threads.
// ---------------------------------------------------------------------------
__global__ __launch_bounds__(256)
void pass2_kernel(const float* __restrict__ a, const float* __restrict__ x,
                  const unsigned short* __restrict__ Vb, const float* __restrict__ fcb,
                  const float* __restrict__ my, float* __restrict__ out)
{
    __shared__ float4 xs[4][32];
    __shared__ float4 mys[64];
    const int t = threadIdx.x, wave = t >> 6, lane = t & 63;
    const int l15 = lane & 15, l4 = lane >> 4;
    const int blk = blockIdx.x, b = blk >> 9, lb = blk & 511;
    const long base = (long)b * NPTS + (long)lb * 512;

    if (t < 64) { const float* mq = my + t*3; mys[t] = make_float4(mq[0], mq[1], mq[2], 0.f); }

    // B fragments in registers: B[k][n=o], lane: o = l15+16ct, k = 32c + l4*8+j
    bf16x8 bfr[5][2];
    {
        const unsigned short* vb = Vb + b * 5120;
        #pragma unroll
        for (int c = 0; c < 5; ++c)
            #pragma unroll
            for (int ct = 0; ct < 2; ++ct) {
                bf16x8 tmp;
                #pragma unroll
                for (int j = 0; j < 8; ++j) {
                    unsigned short uv = vb[(32*c + l4*8 + j) * 32 + l15 + 16*ct];
                    tmp[j] = __builtin_bit_cast(__bf16, uv);
                }
                bfr[c][ct] = tmp;
            }
    }
    const float bias0 = fcb[l15], bias1 = fcb[l15 + 16];
    __syncthreads();

    for (int ci = wave; ci < 16; ci += 4) {
        const long p0 = base + ((long)ci << 5);
        if (lane < 32) {
            const float* xq = x + (p0 + lane) * 3;
            xs[wave][lane] = make_float4(xq[0], xq[1], xq[2], 0.f);
        }
        // residual A fragment: A[m=p_local][k=i], lane: p = l15(+16rt), i = l4*8+j
        bf16x8 afr[2];
        #pragma unroll
        for (int rt = 0; rt < 2; ++rt) {
            const float* ap = a + (p0 + l15 + 16*rt) * 32 + l4*8;
            float4 a0 = *(const float4*)ap;
            float4 a1 = *(const float4*)(ap + 4);
            afr[rt][0] = (__bf16)a0.x; afr[rt][1] = (__bf16)a0.y;
            afr[rt][2] = (__bf16)a0.z; afr[rt][3] = (__bf16)a0.w;
            afr[rt][4] = (__bf16)a1.x; afr[rt][5] = (__bf16)a1.y;
            afr[rt][6] = (__bf16)a1.z; afr[rt][7] = (__bf16)a1.w;
        }
        float4 xp0 = xs[wave][l15];
        float4 xp1 = xs[wave][l15 + 16];
        bf16x8 ac[2][2], as_[2][2];   // [rt][gtile]
        #pragma unroll
        for (int j = 0; j < 8; ++j) {
            float4 mA = mys[l4*8 + j];
            float4 mB = mys[32 + l4*8 + j];
            float dA0 = xp0.x*mA.x + xp0.y*mA.y + xp0.z*mA.z;
            float dB0 = xp0.x*mB.x + xp0.y*mB.y + xp0.z*mB.z;
            float dA1 = xp1.x*mA.x + xp1.y*mA.y + xp1.z*mA.z;
            float dB1 = xp1.x*mB.x + xp1.y*mB.y + xp1.z*mB.z;
            ac[0][0][j]  = (__bf16)__builtin_amdgcn_cosf(dA0);
            as_[0][0][j] = (__bf16)__builtin_amdgcn_sinf(dA0);
            ac[0][1][j]  = (__bf16)__builtin_amdgcn_cosf(dB0);
            as_[0][1][j] = (__bf16)__builtin_amdgcn_sinf(dB0);
            ac[1][0][j]  = (__bf16)__builtin_amdgcn_cosf(dA1);
            as_[1][0][j] = (__bf16)__builtin_amdgcn_sinf(dA1);
            ac[1][1][j]  = (__bf16)__builtin_amdgcn_cosf(dB1);
            as_[1][1][j] = (__bf16)__builtin_amdgcn_sinf(dB1);
        }
        #pragma unroll
        for (int rt = 0; rt < 2; ++rt)
            #pragma unroll
            for (int ct = 0; ct < 2; ++ct) {
                f32x4 acc = f32x4{0.f, 0.f, 0.f, 0.f};
                acc = __builtin_amdgcn_mfma_f32_16x16x32_bf16(ac[rt][0],  bfr[0][ct], acc, 0, 0, 0);
                acc = __builtin_amdgcn_mfma_f32_16x16x32_bf16(ac[rt][1],  bfr[1][ct], acc, 0, 0, 0);
                acc = __builtin_amdgcn_mfma_f32_16x16x32_bf16(as_[rt][0], bfr[2][ct], acc, 0, 0, 0);
                acc = __builtin_amdgcn_mfma_f32_16x16x32_bf16(as_[rt][1], bfr[3][ct], acc, 0, 0, 0);
                acc = __builtin_amdgcn_mfma_f32_16x16x32_bf16(afr[rt],    bfr[4][ct], acc, 0, 0, 0);
                float bias = ct ? bias1 : bias0;
                #pragma unroll
                for (int r = 0; r < 4; ++r) {
                    long p = p0 + 16*rt + l4*4 + r;
                    out[p * 32 + l15 + 16*ct] = gelu_tanh(acc[r] + bias);
                }
            }
    }
}

// ---------------------------------------------------------------------------
extern "C" void kernel_launch(void* const* d_in, const int* in_sizes, int n_in,
                              void* d_out, int out_size, void* d_ws, size_t ws_size,
                              hipStream_t stream)
{
    const float* a   = (const float*)d_in[0];
    const float* x   = (const float*)d_in[1];
    const float* ma  = (const float*)d_in[3];
    const float* mx  = (const float*)d_in[4];
    const float* my  = (const float*)d_in[5];
    const float* mu  = (const float*)d_in[6];
    const float* fcw = (const float*)d_in[7];
    const float* fcb = (const float*)d_in[8];
    float* out = (float*)d_out;

    int NPB = 256;
    while (NPB > 32) {
        size_t need = (size_t)NB * NPB * 4096 * 4 + (size_t)NB * 4096 * 4
                    + (size_t)NB * 5120 * 2 + 256;
        if (need <= ws_size) break;
        NPB >>= 1;
    }
    float* part = (float*)d_ws;
    float* Wf = part + (size_t)NB * NPB * 4096;
    unsigned short* Vb = (unsigned short*)(Wf + NB * 4096);

    pass1_kernel<<<NB * NPB, 256, 0, stream>>>(a, x, mx, part, NPB);
    reduceW_kernel<<<NB * 128, 256, 0, stream>>>(part, Wf, NPB);
    vmat_kernel<<<NB, 256, 0, stream>>>(Wf, ma, mu, fcw, Vb);
    pass2_kernel<<<NB * 512, 256, 0, stream>>>(a, x, Vb, fcb, my, out);
}